// Round 20
// baseline (307.838 us; speedup 1.0000x reference)
//
#include <hip/hip_runtime.h>
#include <hip/hip_bf16.h>

#define NN 16384
#define GG 2048
#define KNN 16
#define EE (NN*KNN)
#define NL 4

typedef _Float16 f16;
typedef _Float16 half8 __attribute__((ext_vector_type(8)));
typedef _Float16 half4 __attribute__((ext_vector_type(4)));
typedef float f32x4 __attribute__((ext_vector_type(4)));
typedef unsigned long long u64;

// gelu tanh-approx in sigmoid form: x*sigmoid(2y), y=a(x+b x^3)
__device__ __forceinline__ float gelu_tanh(float x) {
  float s = x*x;
  float u = __fmaf_rn(-0.0713548194f, s, -1.5957691216f);   // -2ab*s - 2a
  float p = __expf(x*u);
  return x * __builtin_amdgcn_rcpf(1.0f + p);
}

__device__ __forceinline__ int mbcnt64(u64 m) {
  return __builtin_amdgcn_mbcnt_hi((unsigned)(m >> 32),
         __builtin_amdgcn_mbcnt_lo((unsigned)m, 0));
}

// ---------------- pos -> SoA ---------------------------------------------------------
__global__ __launch_bounds__(256) void possoa_kernel(const float* __restrict__ pos,
    float* __restrict__ posx, float* __restrict__ posy, float* __restrict__ posz) {
  int n = blockIdx.x*256 + threadIdx.x;
  posx[n] = pos[(size_t)n*3+0];
  posy[n] = pos[(size_t)n*3+1];
  posz[n] = pos[(size_t)n*3+2];
}

// ---------------- kNN v9: index-carrying chain, no emit-loop recompute --------------
// R18/R19: emit loop rematerialized d2 (VGPR=28, FETCH 856KB); LDS fix cost
// occupancy. v9: carry j through the 4-deep sorted chain (+5 VALU/iter); emit
// straight from (c_q,j_q) when (a) no lane saturated and (b) tie count == needed
// (then the selected SET is exact regardless of tie order; final u64 rank-sort
// orders by (d2,j)). Else: old exact u64 16-deep fallback (bit-identical).
#define INS(kk) { bool sw = key < kk; u64 tmp = kk; kk = sw ? key : kk; key = sw ? tmp : key; }

__global__ __launch_bounds__(256) void knn_kernel(const float* __restrict__ posx,
    const float* __restrict__ posy, const float* __restrict__ posz,
    int* __restrict__ srci, float* __restrict__ dedge) {
  __shared__ u64 sel[4][16];            // per-wave survivor slots (512 B)
  int tid = threadIdx.x;
  int wv = tid >> 6;
  int node = blockIdx.x*4 + wv;
  int lane = tid & 63;
  int base = node & ~(GG-1);
  float qx = posx[node], qy = posy[node], qz = posz[node];

  float c0 = 3.4e38f, c1 = 3.4e38f, c2 = 3.4e38f, c3 = 3.4e38f;
  int j0 = 0, j1 = 0, j2 = 0, j3 = 0;
  #pragma unroll
  for (int it = 0; it < 32; ++it) {
    int jl = it*64 + lane;
    int j = base + jl;
    float dx = __fsub_rn(qx, posx[j]);
    float dy = __fsub_rn(qy, posy[j]);
    float dz = __fsub_rn(qz, posz[j]);
    float x = __fadd_rn(__fadd_rn(__fmul_rn(dx,dx), __fmul_rn(dy,dy)), __fmul_rn(dz,dz));
    int jx = jl;
    { bool sw = x < c0; float nc = sw?x:c0, oc = sw?c0:x; int nj = sw?jx:j0, oj = sw?j0:jx;
      c0 = nc; j0 = nj; x = oc; jx = oj; }
    { bool sw = x < c1; float nc = sw?x:c1, oc = sw?c1:x; int nj = sw?jx:j1, oj = sw?j1:jx;
      c1 = nc; j1 = nj; x = oc; jx = oj; }
    { bool sw = x < c2; float nc = sw?x:c2, oc = sw?c2:x; int nj = sw?jx:j2, oj = sw?j2:jx;
      c2 = nc; j2 = nj; x = oc; jx = oj; }
    { bool sw = x < c3; c3 = sw?x:c3; j3 = sw?jx:j3; }
  }
  // bit-descend: T = largest t with #{d2 < t} < 16  ==> Tf = 16th-smallest d2
  unsigned T = 0;
  for (int b = 30; b >= 0; --b) {
    unsigned tb = T | (1u << b);
    float tf = __uint_as_float(tb);
    int cnt = __popcll(__ballot(c0 < tf)) + __popcll(__ballot(c1 < tf))
            + __popcll(__ballot(c2 < tf)) + __popcll(__ballot(c3 < tf));
    if (cnt < 16) T = tb;
  }
  float Tf = __uint_as_float(T);
  u64 ml0 = __ballot(c0 < Tf), ml1 = __ballot(c1 < Tf),
      ml2 = __ballot(c2 < Tf), ml3 = __ballot(c3 < Tf);
  u64 mt0 = __ballot(c0 == Tf), mt1 = __ballot(c1 == Tf),
      mt2 = __ballot(c2 == Tf), mt3 = __ballot(c3 == Tf);
  int cless = __popcll(ml0) + __popcll(ml1) + __popcll(ml2) + __popcll(ml3);
  int tiecnt = __popcll(mt0) + __popcll(mt1) + __popcll(mt2) + __popcll(mt3);
  if (!__any(c3 <= Tf) && tiecnt == 16 - cless) {
    // fast emit from register lists (no recompute). Slots are a permutation of
    // 0..15; final rank loop re-orders by full (d2,j) key.
    int offb = 0;
    if (c0 < Tf) sel[wv][offb + mbcnt64(ml0)] = ((u64)__float_as_uint(c0) << 32) | (unsigned)j0;
    offb += (int)__popcll(ml0);
    if (c1 < Tf) sel[wv][offb + mbcnt64(ml1)] = ((u64)__float_as_uint(c1) << 32) | (unsigned)j1;
    offb += (int)__popcll(ml1);
    if (c2 < Tf) sel[wv][offb + mbcnt64(ml2)] = ((u64)__float_as_uint(c2) << 32) | (unsigned)j2;
    offb += (int)__popcll(ml2);
    if (c3 < Tf) sel[wv][offb + mbcnt64(ml3)] = ((u64)__float_as_uint(c3) << 32) | (unsigned)j3;
    offb += (int)__popcll(ml3);
    if (c0 == Tf) sel[wv][offb + mbcnt64(mt0)] = ((u64)__float_as_uint(c0) << 32) | (unsigned)j0;
    offb += (int)__popcll(mt0);
    if (c1 == Tf) sel[wv][offb + mbcnt64(mt1)] = ((u64)__float_as_uint(c1) << 32) | (unsigned)j1;
    offb += (int)__popcll(mt1);
    if (c2 == Tf) sel[wv][offb + mbcnt64(mt2)] = ((u64)__float_as_uint(c2) << 32) | (unsigned)j2;
    offb += (int)__popcll(mt2);
    if (c3 == Tf) sel[wv][offb + mbcnt64(mt3)] = ((u64)__float_as_uint(c3) << 32) | (unsigned)j3;
  } else {
    // exact fallback (rare): 16-deep per-lane u64 list, full rescan
    u64 k0=~0ull,k1=~0ull,k2=~0ull,k3=~0ull,k4=~0ull,k5=~0ull,k6=~0ull,k7=~0ull,
        k8=~0ull,k9=~0ull,k10=~0ull,k11=~0ull,k12=~0ull,k13=~0ull,k14=~0ull,k15=~0ull;
    for (int it = 0; it < 32; ++it) {
      int jl = it*64 + lane;
      int j = base + jl;
      float dx = __fsub_rn(qx, posx[j]);
      float dy = __fsub_rn(qy, posy[j]);
      float dz = __fsub_rn(qz, posz[j]);
      float d2 = __fadd_rn(__fadd_rn(__fmul_rn(dx,dx), __fmul_rn(dy,dy)), __fmul_rn(dz,dz));
      u64 key = ((u64)__float_as_uint(d2) << 32) | (unsigned)jl;
      if (key < k15) {
        INS(k0) INS(k1) INS(k2) INS(k3) INS(k4) INS(k5) INS(k6) INS(k7)
        INS(k8) INS(k9) INS(k10) INS(k11) INS(k12) INS(k13) INS(k14) INS(k15)
      }
    }
    u64 res = 0;
    for (int r = 0; r < 16; ++r) {
      u64 cur = k0;
      #pragma unroll
      for (int s = 1; s < 64; s <<= 1) {
        u64 o = __shfl_xor(cur, s, 64);
        cur = (o < cur) ? o : cur;
      }
      bool own = (k0 == cur);
      k0 = own?k1:k0;  k1 = own?k2:k1;  k2 = own?k3:k2;  k3 = own?k4:k3;
      k4 = own?k5:k4;  k5 = own?k6:k5;  k6 = own?k7:k6;  k7 = own?k8:k7;
      k8 = own?k9:k8;  k9 = own?k10:k9; k10= own?k11:k10; k11= own?k12:k11;
      k12= own?k13:k12; k13= own?k14:k13; k14= own?k15:k14; k15= own?~0ull:k15;
      if (lane == r) sel[wv][r] = cur;
    }
  }
  // rank 16 survivors (broadcast LDS reads; within-wave, no barrier)
  if (lane < KNN) {
    u64 e = sel[wv][lane];
    int rank = 0;
    #pragma unroll
    for (int k2r = 0; k2r < 16; ++k2r) rank += (sel[wv][k2r] < e) ? 1 : 0;
    int j = (int)(e & 0xffffffffu);
    float d2v = __uint_as_float((unsigned)(e >> 32));
    srci[node*KNN + rank] = base + j;
    dedge[node*KNN + rank] = sqrtf(__fadd_rn(d2v, 1e-12f));
  }
}

// ---------------- weight transpose + f16 convert (transposed [col][k] layouts) -------
__global__ __launch_bounds__(256) void prep_kernel(
    const float* __restrict__ Wb2, const float* __restrict__ Wk,
    const float* __restrict__ W1, const float* __restrict__ W2,
    f16* __restrict__ Wb2t, f16* __restrict__ Wkt,
    f16* __restrict__ W1t, f16* __restrict__ W2t) {
  int i = blockIdx.x*256 + threadIdx.x;
  if (i < 16384) {
    int c = i >> 7, k = i & 127;
    Wb2t[i] = (f16)Wb2[k*128 + c];
    return;
  }
  i -= 16384;
  if (i < 65536) {
    int l = i >> 14, r = i & 16383; int c = r >> 7, k = r & 127;
    Wkt[i] = (f16)Wk[l*16384 + k*128 + c];
    return;
  }
  i -= 65536;
  if (i < 262144) {
    int l = i >> 16, r = i & 65535; int c = r >> 7, k = r & 127;   // c<512,k<128
    W1t[i] = (f16)W1[l*65536 + k*512 + c];
    return;
  }
  i -= 262144;
  if (i < 262144) {
    int l = i >> 16, r = i & 65535; int c = r >> 9, k = r & 511;   // c<128,k<512
    W2t[i] = (f16)W2[l*65536 + k*128 + c];
  }
}

// ---------------- embed: h = x[N,65] @ We[65,128] (f32 VALU) -------------------------
__global__ __launch_bounds__(256) void embed_kernel(const float* __restrict__ x,
    const float* __restrict__ We, float* __restrict__ h) {
  int t = threadIdx.x;
  int n = blockIdx.x*8 + (t >> 5);
  int q = (t & 31) * 4;
  f32x4 acc = {0.f,0.f,0.f,0.f};
  const float* xr = x + n*65;
  for (int k = 0; k < 65; ++k) {
    float xv = xr[k];
    f32x4 wv = *(const f32x4*)(We + k*128 + q);
    acc += xv * wv;
  }
  *(f32x4*)(h + (size_t)n*128 + q) = acc;
}

// ---------------- edge basis v5: Wb2 staged in LDS -----------------------------------
__global__ __launch_bounds__(256) void basis_kernel(const float* __restrict__ dedge,
    const float* __restrict__ Wb1, const float* __restrict__ bb1,
    const f16* __restrict__ Wb2t, const float* __restrict__ bb2,
    f16* __restrict__ kernA) {
  __shared__ f16 Wb2s[128][136];  // 34.8KB, padded: B-frag ds_read_b128 2-way max
  __shared__ f16 kb[64][136];     // 17.4KB, rows w*16.. private per wave
  int t = threadIdx.x;
  #pragma unroll
  for (int it = 0; it < 8; ++it) {      // stage Wb2t (32KB) coalesced
    int idx = it*256 + t;
    int row = idx >> 4, k8 = (idx & 15) * 8;
    *(half8*)&Wb2s[row][k8] = *(const half8*)&Wb2t[row*128 + k8];
  }
  __syncthreads();
  int w = t >> 6, l = t & 63;
  int row4 = l >> 4, rlo = l & 15;
  #pragma unroll
  for (int tt = 0; tt < 2; ++tt) {
    size_t Tg = (size_t)blockIdx.x*8 + (size_t)w*2 + tt;
    float d = dedge[Tg*16 + rlo];
    float d2 = d*d, d3 = d2*d;
    half8 a[4];
    #pragma unroll
    for (int kc = 0; kc < 4; ++kc) {
      int k0 = kc*32 + row4*8;
      f32x4 w1a = *(const f32x4*)&Wb1[k0],     w1b = *(const f32x4*)&Wb1[k0+4];
      f32x4 w2a = *(const f32x4*)&Wb1[128+k0], w2b = *(const f32x4*)&Wb1[128+k0+4];
      f32x4 w3a = *(const f32x4*)&Wb1[256+k0], w3b = *(const f32x4*)&Wb1[256+k0+4];
      f32x4 bba = *(const f32x4*)&bb1[k0],     bbb = *(const f32x4*)&bb1[k0+4];
      #pragma unroll
      for (int j = 0; j < 4; ++j) {
        a[kc][j]   = (f16)gelu_tanh(d*w1a[j] + d2*w2a[j] + d3*w3a[j] + bba[j]);
        a[kc][4+j] = (f16)gelu_tanh(d*w1b[j] + d2*w2b[j] + d3*w3b[j] + bbb[j]);
      }
    }
    f32x4 acc[8];
    #pragma unroll
    for (int nt = 0; nt < 8; ++nt) {
      acc[nt] = (f32x4){0.f,0.f,0.f,0.f};
      #pragma unroll
      for (int kc = 0; kc < 4; ++kc) {
        half8 b = *(const half8*)&Wb2s[nt*16 + rlo][kc*32 + row4*8];
        acc[nt] = __builtin_amdgcn_mfma_f32_16x16x32_f16(a[kc], b, acc[nt], 0, 0, 0);
      }
    }
    #pragma unroll
    for (int nt = 0; nt < 8; ++nt) {
      float bias = bb2[nt*16 + rlo];
      #pragma unroll
      for (int j = 0; j < 4; ++j)
        kb[w*16 + row4*4 + j][nt*16 + rlo] = (f16)gelu_tanh(acc[nt][j] + bias);
    }
    #pragma unroll
    for (int kc = 0; kc < 4; ++kc) {
      half8 v = *(const half8*)&kb[w*16 + rlo][kc*32 + row4*8];
      *(half8*)&kernA[((Tg*4 + kc)*64 + l)*8] = v;
    }
  }
}

// ---------------- fused layer v8 (R17-exact: 44us known-good) -----------------------
__global__ __launch_bounds__(512) void layer_kernel(const f16* __restrict__ kernA,
    const f16* __restrict__ Wkt_l, const int* __restrict__ srci,
    const float* __restrict__ hin,
    const float* __restrict__ lng, const float* __restrict__ lnb,
    const f16* __restrict__ W1t_l, const float* __restrict__ b1_l,
    const f16* __restrict__ W2t_l, const float* __restrict__ b2_l,
    float* __restrict__ hout) {
  __shared__ __align__(16) char smem_u[34816];  // union: Wkts[128][136] | y1[32][520]
  f16 (*Wkts)[136] = (f16(*)[136])smem_u;
  f16 (*y1)[520]   = (f16(*)[520])smem_u;
  __shared__ float aggl[32][132];   // 16.9KB conv output (wave-private rows)
  __shared__ f16 zl[32][136];       // 8.7KB  LN output
  int t = threadIdx.x;              // 0..511
  int w = t >> 6, l = t & 63;       // 8 waves
  int row4 = l >> 4, rlo = l & 15;
  int n0 = blockIdx.x * 32;

  // stage Wkt (32KB) coalesced: 2048 half8 chunks over 512 threads
  #pragma unroll
  for (int it = 0; it < 4; ++it) {
    int idx = it*512 + t;
    int row = idx >> 4, k8 = (idx & 15) * 8;
    *(half8*)&Wkts[row][k8] = *(const half8*)&Wkt_l[row*128 + k8];
  }

  int sidxA[4][4];
  #pragma unroll
  for (int m = 0; m < 4; ++m)
    #pragma unroll
    for (int j = 0; j < 4; ++j)
      sidxA[m][j] = srci[(n0 + w*4 + m)*16 + row4*4 + j];
  __syncthreads();

  // ---- conv node-major: kernA once, hv batched, weights from LDS
  #pragma unroll
  for (int m = 0; m < 4; ++m) {
    int node = n0 + w*4 + m;
    half8 a[4];
    #pragma unroll
    for (int kc = 0; kc < 4; ++kc)
      a[kc] = *(const half8*)&kernA[(((size_t)node*4 + kc)*64 + l)*8];
    float hv[8][4];
    #pragma unroll
    for (int nt = 0; nt < 8; ++nt)
      #pragma unroll
      for (int j = 0; j < 4; ++j)
        hv[nt][j] = hin[(size_t)sidxA[m][j]*128 + nt*16 + rlo];
    #pragma unroll
    for (int nt = 0; nt < 8; ++nt) {
      half8 bf4[4];
      #pragma unroll
      for (int kc = 0; kc < 4; ++kc)
        bf4[kc] = *(const half8*)&Wkts[nt*16 + rlo][kc*32 + row4*8];
      f32x4 acc = {0.f,0.f,0.f,0.f};
      #pragma unroll
      for (int kc = 0; kc < 4; ++kc)
        acc = __builtin_amdgcn_mfma_f32_16x16x32_f16(a[kc], bf4[kc], acc, 0, 0, 0);
      float p = 0.f;
      #pragma unroll
      for (int j = 0; j < 4; ++j) p += acc[j] * hv[nt][j];
      p += __shfl_xor(p, 16, 64);
      p += __shfl_xor(p, 32, 64);
      if (l < 16) aggl[w*4 + m][nt*16 + l] = p;
    }
  }
  // ---- LayerNorm (aggl rows wave-private -> no barrier; within-wave LDS RAW ok)
  {
    int row = w*4 + row4;
    int cb = rlo*8;
    f32x4 va = *(const f32x4*)&aggl[row][cb];
    f32x4 vb = *(const f32x4*)&aggl[row][cb+4];
    float s = va[0]+va[1]+va[2]+va[3] + vb[0]+vb[1]+vb[2]+vb[3];
    #pragma unroll
    for (int st = 1; st < 16; st <<= 1) s += __shfl_xor(s, st, 64);
    float mu = s * (1.f/128.f);
    f32x4 da = va - mu, db = vb - mu;
    float s2 = da[0]*da[0]+da[1]*da[1]+da[2]*da[2]+da[3]*da[3]
             + db[0]*db[0]+db[1]*db[1]+db[2]*db[2]+db[3]*db[3];
    #pragma unroll
    for (int st = 1; st < 16; st <<= 1) s2 += __shfl_xor(s2, st, 64);
    float inv = rsqrtf(s2*(1.f/128.f) + 1e-5f);
    f32x4 ga = *(const f32x4*)&lng[cb], gb = *(const f32x4*)&lng[cb+4];
    f32x4 ba = *(const f32x4*)&lnb[cb], bb = *(const f32x4*)&lnb[cb+4];
    f32x4 za = da*inv*ga + ba, zb = db*inv*gb + bb;
    half8 hz = { (f16)za[0],(f16)za[1],(f16)za[2],(f16)za[3],
                 (f16)zb[0],(f16)zb[1],(f16)zb[2],(f16)zb[3] };
    *(half8*)&zl[row][cb] = hz;
  }
  __syncthreads();   // zl ready for all waves; also separates Wkts reads from y1 writes
  // ---- W1: 32 nt over 8 waves = 4 nt/wave; 2 M-tiles share each B-frag (1:2)
  half8 aza[4], azb[4];
  #pragma unroll
  for (int kc = 0; kc < 4; ++kc) {
    aza[kc] = *(const half8*)&zl[rlo][kc*32 + row4*8];
    azb[kc] = *(const half8*)&zl[16 + rlo][kc*32 + row4*8];
  }
  #pragma unroll
  for (int ntl = 0; ntl < 4; ++ntl) {
    int col = (w*4 + ntl)*16 + rlo;
    f32x4 accA = {0.f,0.f,0.f,0.f}, accB = {0.f,0.f,0.f,0.f};
    #pragma unroll
    for (int kc = 0; kc < 4; ++kc) {
      half8 b = *(const half8*)&W1t_l[(size_t)col*128 + kc*32 + row4*8];
      accA = __builtin_amdgcn_mfma_f32_16x16x32_f16(aza[kc], b, accA, 0, 0, 0);
      accB = __builtin_amdgcn_mfma_f32_16x16x32_f16(azb[kc], b, accB, 0, 0, 0);
    }
    float bias = b1_l[col];
    #pragma unroll
    for (int j = 0; j < 4; ++j) {
      y1[row4*4 + j][col]      = (f16)gelu_tanh(accA[j] + bias);
      y1[16 + row4*4 + j][col] = (f16)gelu_tanh(accB[j] + bias);
    }
  }
  __syncthreads();
  // ---- W2: 1 col-tile/wave; K-loop: 1 B-load + 2 ds_read + 2 MFMA
  {
    int col = w*16 + rlo;
    f32x4 accA = {0.f,0.f,0.f,0.f}, accB = {0.f,0.f,0.f,0.f};
    #pragma unroll
    for (int kc2 = 0; kc2 < 16; ++kc2) {
      half8 b   = *(const half8*)&W2t_l[(size_t)col*512 + kc2*32 + row4*8];
      half8 a2a = *(const half8*)&y1[rlo][kc2*32 + row4*8];
      half8 a2b = *(const half8*)&y1[16 + rlo][kc2*32 + row4*8];
      accA = __builtin_amdgcn_mfma_f32_16x16x32_f16(a2a, b, accA, 0, 0, 0);
      accB = __builtin_amdgcn_mfma_f32_16x16x32_f16(a2b, b, accB, 0, 0, 0);
    }
    float bias = b2_l[col];
    #pragma unroll
    for (int j = 0; j < 4; ++j) {
      size_t na = (size_t)(n0 + row4*4 + j);
      size_t nb = (size_t)(n0 + 16 + row4*4 + j);
      hout[na*128 + col] = accA[j] + bias + hin[na*128 + col];
      hout[nb*128 + col] = accB[j] + bias + hin[nb*128 + col];
    }
  }
}

// ---------------- readout ------------------------------------------------------------
__global__ __launch_bounds__(256) void readout_kernel(const float* __restrict__ h,
    const float* __restrict__ Wr, const float* __restrict__ br, float* __restrict__ out) {
  int n = blockIdx.x*256 + threadIdx.x;
  f32x4 acc = {0.f,0.f,0.f,0.f};
  #pragma unroll
  for (int cb = 0; cb < 32; ++cb) {
    f32x4 hv = *(const f32x4*)(h + (size_t)n*128 + cb*4);
    f32x4 wv = *(const f32x4*)(Wr + cb*4);
    acc += hv*wv;
  }
  out[n] = acc[0]+acc[1]+acc[2]+acc[3] + br[0];
}

extern "C" void kernel_launch(void* const* d_in, const int* in_sizes, int n_in,
                              void* d_out, int out_size, void* d_ws, size_t ws_size,
                              hipStream_t stream) {
  const float* x   = (const float*)d_in[0];
  const float* pos = (const float*)d_in[1];
  const float* We  = (const float*)d_in[3];
  const float* Wb1 = (const float*)d_in[4];
  const float* bb1 = (const float*)d_in[5];
  const float* Wb2 = (const float*)d_in[6];
  const float* bb2 = (const float*)d_in[7];
  const float* Wk  = (const float*)d_in[8];
  const float* lng = (const float*)d_in[9];
  const float* lnb = (const float*)d_in[10];
  const float* W1  = (const float*)d_in[11];
  const float* b1  = (const float*)d_in[12];
  const float* W2  = (const float*)d_in[13];
  const float* b2  = (const float*)d_in[14];
  const float* Wr  = (const float*)d_in[15];
  const float* br  = (const float*)d_in[16];
  float* out = (float*)d_out;

  char* p = (char*)d_ws;
  int*   srci  = (int*)p;     p += (size_t)EE*4;
  float* dedge = (float*)p;   p += (size_t)EE*4;
  f16*   kernA = (f16*)p;     p += (size_t)EE*128*2;
  float* hA    = (float*)p;   p += (size_t)NN*128*4;
  float* hB    = (float*)p;   p += (size_t)NN*128*4;
  f16* Wb2t    = (f16*)p;     p += (size_t)16384*2;
  f16* Wkt     = (f16*)p;     p += (size_t)65536*2;
  f16* W1t     = (f16*)p;     p += (size_t)262144*2;
  f16* W2t     = (f16*)p;     p += (size_t)262144*2;
  float* posx  = (float*)p;   p += (size_t)NN*4;
  float* posy  = (float*)p;   p += (size_t)NN*4;
  float* posz  = (float*)p;   p += (size_t)NN*4;

  possoa_kernel<<<NN/256, 256, 0, stream>>>(pos, posx, posy, posz);
  prep_kernel<<<2368, 256, 0, stream>>>(Wb2, Wk, W1, W2, Wb2t, Wkt, W1t, W2t);
  knn_kernel<<<NN/4, 256, 0, stream>>>(posx, posy, posz, srci, dedge);
  basis_kernel<<<2048, 256, 0, stream>>>(dedge, Wb1, bb1, Wb2t, bb2, kernA);
  embed_kernel<<<NN/8, 256, 0, stream>>>(x, We, hA);
  float* hin = hA;
  for (int lyr = 0; lyr < NL; ++lyr) {
    float* hout = (hin == hA) ? hB : hA;
    layer_kernel<<<NN/32, 512, 0, stream>>>(kernA, Wkt + lyr*16384, srci, hin,
        lng + lyr*128, lnb + lyr*128,
        W1t + (size_t)lyr*65536, b1 + lyr*512, W2t + (size_t)lyr*65536, b2 + lyr*128, hout);
    hin = hout;
  }
  readout_kernel<<<NN/256, 256, 0, stream>>>(hin, Wr, br, out);
}

// Round 21
// 284.162 us; speedup vs baseline: 1.0833x; 1.0833x over previous
//
#include <hip/hip_runtime.h>
#include <hip/hip_bf16.h>

#define NN 16384
#define GG 2048
#define KNN 16
#define EE (NN*KNN)
#define NL 4

typedef _Float16 f16;
typedef _Float16 half8 __attribute__((ext_vector_type(8)));
typedef _Float16 half4 __attribute__((ext_vector_type(4)));
typedef float f32x4 __attribute__((ext_vector_type(4)));
typedef unsigned long long u64;

// gelu tanh-approx in sigmoid form: x*sigmoid(2y), y=a(x+b x^3)
__device__ __forceinline__ float gelu_tanh(float x) {
  float s = x*x;
  float u = __fmaf_rn(-0.0713548194f, s, -1.5957691216f);   // -2ab*s - 2a
  float p = __expf(x*u);
  return x * __builtin_amdgcn_rcpf(1.0f + p);
}

__device__ __forceinline__ int mbcnt64(u64 m) {
  return __builtin_amdgcn_mbcnt_hi((unsigned)(m >> 32),
         __builtin_amdgcn_mbcnt_lo((unsigned)m, 0));
}

// ---------------- pos -> SoA ---------------------------------------------------------
__global__ __launch_bounds__(256) void possoa_kernel(const float* __restrict__ pos,
    float* __restrict__ posx, float* __restrict__ posy, float* __restrict__ posz) {
  int n = blockIdx.x*256 + threadIdx.x;
  posx[n] = pos[(size_t)n*3+0];
  posy[n] = pos[(size_t)n*3+1];
  posz[n] = pos[(size_t)n*3+2];
}

// ---------------- kNN v7 (FROZEN PERMANENTLY: 48.4us best of 8 attempts) ------------
// VGPR=28 via compiler rematerialization of d2s in the emit loop = 8 waves/SIMD
// occupancy; every attempt to "fix" the recompute (LDS, index-carry) cost registers
// or LDS and regressed. Occupancy IS the optimization here.
__global__ __launch_bounds__(256) void knn_kernel(const float* __restrict__ posx,
    const float* __restrict__ posy, const float* __restrict__ posz,
    int* __restrict__ srci, float* __restrict__ dedge) {
  __shared__ u64 sel[4][16];            // per-wave survivor slots (512 B)
  int tid = threadIdx.x;
  int wv = tid >> 6;
  int node = blockIdx.x*4 + wv;
  int lane = tid & 63;
  int base = node & ~(GG-1);
  float qx = posx[node], qy = posy[node], qz = posz[node];

  float d2s[32];
  float c0 = 3.4e38f, c1 = 3.4e38f, c2 = 3.4e38f, c3 = 3.4e38f;
  #pragma unroll
  for (int it = 0; it < 32; ++it) {
    int j = base + it*64 + lane;
    float dx = __fsub_rn(qx, posx[j]);
    float dy = __fsub_rn(qy, posy[j]);
    float dz = __fsub_rn(qz, posz[j]);
    float d2 = __fadd_rn(__fadd_rn(__fmul_rn(dx,dx), __fmul_rn(dy,dy)), __fmul_rn(dz,dz));
    d2s[it] = d2;
    float x = d2;
    float t0 = fminf(c0, x); x = fmaxf(c0, x); c0 = t0;
    float t1 = fminf(c1, x); x = fmaxf(c1, x); c1 = t1;
    float t2 = fminf(c2, x); x = fmaxf(c2, x); c2 = t2;
    c3 = fminf(c3, x);
  }
  unsigned T = 0;
  for (int b = 30; b >= 0; --b) {
    unsigned tb = T | (1u << b);
    float tf = __uint_as_float(tb);
    int cnt = __popcll(__ballot(c0 < tf)) + __popcll(__ballot(c1 < tf))
            + __popcll(__ballot(c2 < tf)) + __popcll(__ballot(c3 < tf));
    if (cnt < 16) T = tb;
  }
  float Tf = __uint_as_float(T);
  int cless;
  if (!__any(c3 <= Tf)) {
    cless = __popcll(__ballot(c0 < Tf)) + __popcll(__ballot(c1 < Tf))
          + __popcll(__ballot(c2 < Tf)) + __popcll(__ballot(c3 < Tf));
  } else {
    T = 0;
    for (int b = 30; b >= 0; --b) {
      unsigned tb = T | (1u << b);
      float tf = __uint_as_float(tb);
      int cnt = 0;
      #pragma unroll
      for (int q = 0; q < 32; ++q) cnt += __popcll(__ballot(d2s[q] < tf));
      if (cnt < 16) T = tb;
    }
    Tf = __uint_as_float(T);
    cless = 0;
    #pragma unroll
    for (int q = 0; q < 32; ++q) cless += __popcll(__ballot(d2s[q] < Tf));
  }
  int offb = 0;
  int tieq = 16 - cless;
  #pragma unroll
  for (int it = 0; it < 32; ++it) {
    u64 mless = __ballot(d2s[it] < Tf);
    u64 mtie  = __ballot(d2s[it] == Tf);
    bool store = (d2s[it] < Tf);
    int slot = offb + mbcnt64(mless);
    offb += (int)__popcll(mless);
    if (mtie != 0 && tieq > 0) {
      int tr = mbcnt64(mtie);
      if (d2s[it] == Tf && tr < tieq) { store = true; slot = offb + tr; }
      int take = (int)__popcll(mtie); take = take < tieq ? take : tieq;
      offb += take; tieq -= take;
    }
    if (store)
      sel[wv][slot] = ((u64)__float_as_uint(d2s[it]) << 32) | (unsigned)(it*64 + lane);
  }
  if (lane < KNN) {
    u64 e = sel[wv][lane];
    int rank = 0;
    #pragma unroll
    for (int k2 = 0; k2 < 16; ++k2) rank += (sel[wv][k2] < e) ? 1 : 0;
    int j = (int)(e & 0xffffffffu);
    float d2v = __uint_as_float((unsigned)(e >> 32));
    srci[node*KNN + rank] = base + j;
    dedge[node*KNN + rank] = sqrtf(__fadd_rn(d2v, 1e-12f));
  }
}

// ---------------- weight transpose + f16 convert (transposed [col][k] layouts) -------
__global__ __launch_bounds__(256) void prep_kernel(
    const float* __restrict__ Wb2, const float* __restrict__ Wk,
    const float* __restrict__ W1, const float* __restrict__ W2,
    f16* __restrict__ Wb2t, f16* __restrict__ Wkt,
    f16* __restrict__ W1t, f16* __restrict__ W2t) {
  int i = blockIdx.x*256 + threadIdx.x;
  if (i < 16384) {
    int c = i >> 7, k = i & 127;
    Wb2t[i] = (f16)Wb2[k*128 + c];
    return;
  }
  i -= 16384;
  if (i < 65536) {
    int l = i >> 14, r = i & 16383; int c = r >> 7, k = r & 127;
    Wkt[i] = (f16)Wk[l*16384 + k*128 + c];
    return;
  }
  i -= 65536;
  if (i < 262144) {
    int l = i >> 16, r = i & 65535; int c = r >> 7, k = r & 127;   // c<512,k<128
    W1t[i] = (f16)W1[l*65536 + k*512 + c];
    return;
  }
  i -= 262144;
  if (i < 262144) {
    int l = i >> 16, r = i & 65535; int c = r >> 9, k = r & 511;   // c<128,k<512
    W2t[i] = (f16)W2[l*65536 + k*128 + c];
  }
}

// ---------------- embed: h = x[N,65] @ We[65,128] (f32 VALU) -------------------------
__global__ __launch_bounds__(256) void embed_kernel(const float* __restrict__ x,
    const float* __restrict__ We, float* __restrict__ h) {
  int t = threadIdx.x;
  int n = blockIdx.x*8 + (t >> 5);
  int q = (t & 31) * 4;
  f32x4 acc = {0.f,0.f,0.f,0.f};
  const float* xr = x + n*65;
  for (int k = 0; k < 65; ++k) {
    float xv = xr[k];
    f32x4 wv = *(const f32x4*)(We + k*128 + q);
    acc += xv * wv;
  }
  *(f32x4*)(h + (size_t)n*128 + q) = acc;
}

// ---------------- edge basis v5: Wb2 staged in LDS -----------------------------------
__global__ __launch_bounds__(256) void basis_kernel(const float* __restrict__ dedge,
    const float* __restrict__ Wb1, const float* __restrict__ bb1,
    const f16* __restrict__ Wb2t, const float* __restrict__ bb2,
    f16* __restrict__ kernA) {
  __shared__ f16 Wb2s[128][136];  // 34.8KB, padded: B-frag ds_read_b128 2-way max
  __shared__ f16 kb[64][136];     // 17.4KB, rows w*16.. private per wave
  int t = threadIdx.x;
  #pragma unroll
  for (int it = 0; it < 8; ++it) {      // stage Wb2t (32KB) coalesced
    int idx = it*256 + t;
    int row = idx >> 4, k8 = (idx & 15) * 8;
    *(half8*)&Wb2s[row][k8] = *(const half8*)&Wb2t[row*128 + k8];
  }
  __syncthreads();
  int w = t >> 6, l = t & 63;
  int row4 = l >> 4, rlo = l & 15;
  #pragma unroll
  for (int tt = 0; tt < 2; ++tt) {
    size_t Tg = (size_t)blockIdx.x*8 + (size_t)w*2 + tt;
    float d = dedge[Tg*16 + rlo];
    float d2 = d*d, d3 = d2*d;
    half8 a[4];
    #pragma unroll
    for (int kc = 0; kc < 4; ++kc) {
      int k0 = kc*32 + row4*8;
      f32x4 w1a = *(const f32x4*)&Wb1[k0],     w1b = *(const f32x4*)&Wb1[k0+4];
      f32x4 w2a = *(const f32x4*)&Wb1[128+k0], w2b = *(const f32x4*)&Wb1[128+k0+4];
      f32x4 w3a = *(const f32x4*)&Wb1[256+k0], w3b = *(const f32x4*)&Wb1[256+k0+4];
      f32x4 bba = *(const f32x4*)&bb1[k0],     bbb = *(const f32x4*)&bb1[k0+4];
      #pragma unroll
      for (int j = 0; j < 4; ++j) {
        a[kc][j]   = (f16)gelu_tanh(d*w1a[j] + d2*w2a[j] + d3*w3a[j] + bba[j]);
        a[kc][4+j] = (f16)gelu_tanh(d*w1b[j] + d2*w2b[j] + d3*w3b[j] + bbb[j]);
      }
    }
    f32x4 acc[8];
    #pragma unroll
    for (int nt = 0; nt < 8; ++nt) {
      acc[nt] = (f32x4){0.f,0.f,0.f,0.f};
      #pragma unroll
      for (int kc = 0; kc < 4; ++kc) {
        half8 b = *(const half8*)&Wb2s[nt*16 + rlo][kc*32 + row4*8];
        acc[nt] = __builtin_amdgcn_mfma_f32_16x16x32_f16(a[kc], b, acc[nt], 0, 0, 0);
      }
    }
    #pragma unroll
    for (int nt = 0; nt < 8; ++nt) {
      float bias = bb2[nt*16 + rlo];
      #pragma unroll
      for (int j = 0; j < 4; ++j)
        kb[w*16 + row4*4 + j][nt*16 + rlo] = (f16)gelu_tanh(acc[nt][j] + bias);
    }
    #pragma unroll
    for (int kc = 0; kc < 4; ++kc) {
      half8 v = *(const half8*)&kb[w*16 + rlo][kc*32 + row4*8];
      *(half8*)&kernA[((Tg*4 + kc)*64 + l)*8] = v;
    }
  }
}

// ---------------- fused layer v8 (R17-exact: 44us known-good) -----------------------
__global__ __launch_bounds__(512) void layer_kernel(const f16* __restrict__ kernA,
    const f16* __restrict__ Wkt_l, const int* __restrict__ srci,
    const float* __restrict__ hin,
    const float* __restrict__ lng, const float* __restrict__ lnb,
    const f16* __restrict__ W1t_l, const float* __restrict__ b1_l,
    const f16* __restrict__ W2t_l, const float* __restrict__ b2_l,
    float* __restrict__ hout) {
  __shared__ __align__(16) char smem_u[34816];  // union: Wkts[128][136] | y1[32][520]
  f16 (*Wkts)[136] = (f16(*)[136])smem_u;
  f16 (*y1)[520]   = (f16(*)[520])smem_u;
  __shared__ float aggl[32][132];   // 16.9KB conv output (wave-private rows)
  __shared__ f16 zl[32][136];       // 8.7KB  LN output
  int t = threadIdx.x;              // 0..511
  int w = t >> 6, l = t & 63;       // 8 waves
  int row4 = l >> 4, rlo = l & 15;
  int n0 = blockIdx.x * 32;

  // stage Wkt (32KB) coalesced: 2048 half8 chunks over 512 threads
  #pragma unroll
  for (int it = 0; it < 4; ++it) {
    int idx = it*512 + t;
    int row = idx >> 4, k8 = (idx & 15) * 8;
    *(half8*)&Wkts[row][k8] = *(const half8*)&Wkt_l[row*128 + k8];
  }

  int sidxA[4][4];
  #pragma unroll
  for (int m = 0; m < 4; ++m)
    #pragma unroll
    for (int j = 0; j < 4; ++j)
      sidxA[m][j] = srci[(n0 + w*4 + m)*16 + row4*4 + j];
  __syncthreads();

  // ---- conv node-major: kernA once, hv batched, weights from LDS
  #pragma unroll
  for (int m = 0; m < 4; ++m) {
    int node = n0 + w*4 + m;
    half8 a[4];
    #pragma unroll
    for (int kc = 0; kc < 4; ++kc)
      a[kc] = *(const half8*)&kernA[(((size_t)node*4 + kc)*64 + l)*8];
    float hv[8][4];
    #pragma unroll
    for (int nt = 0; nt < 8; ++nt)
      #pragma unroll
      for (int j = 0; j < 4; ++j)
        hv[nt][j] = hin[(size_t)sidxA[m][j]*128 + nt*16 + rlo];
    #pragma unroll
    for (int nt = 0; nt < 8; ++nt) {
      half8 bf4[4];
      #pragma unroll
      for (int kc = 0; kc < 4; ++kc)
        bf4[kc] = *(const half8*)&Wkts[nt*16 + rlo][kc*32 + row4*8];
      f32x4 acc = {0.f,0.f,0.f,0.f};
      #pragma unroll
      for (int kc = 0; kc < 4; ++kc)
        acc = __builtin_amdgcn_mfma_f32_16x16x32_f16(a[kc], bf4[kc], acc, 0, 0, 0);
      float p = 0.f;
      #pragma unroll
      for (int j = 0; j < 4; ++j) p += acc[j] * hv[nt][j];
      p += __shfl_xor(p, 16, 64);
      p += __shfl_xor(p, 32, 64);
      if (l < 16) aggl[w*4 + m][nt*16 + l] = p;
    }
  }
  // ---- LayerNorm (aggl rows wave-private -> no barrier; within-wave LDS RAW ok)
  {
    int row = w*4 + row4;
    int cb = rlo*8;
    f32x4 va = *(const f32x4*)&aggl[row][cb];
    f32x4 vb = *(const f32x4*)&aggl[row][cb+4];
    float s = va[0]+va[1]+va[2]+va[3] + vb[0]+vb[1]+vb[2]+vb[3];
    #pragma unroll
    for (int st = 1; st < 16; st <<= 1) s += __shfl_xor(s, st, 64);
    float mu = s * (1.f/128.f);
    f32x4 da = va - mu, db = vb - mu;
    float s2 = da[0]*da[0]+da[1]*da[1]+da[2]*da[2]+da[3]*da[3]
             + db[0]*db[0]+db[1]*db[1]+db[2]*db[2]+db[3]*db[3];
    #pragma unroll
    for (int st = 1; st < 16; st <<= 1) s2 += __shfl_xor(s2, st, 64);
    float inv = rsqrtf(s2*(1.f/128.f) + 1e-5f);
    f32x4 ga = *(const f32x4*)&lng[cb], gb = *(const f32x4*)&lng[cb+4];
    f32x4 ba = *(const f32x4*)&lnb[cb], bb = *(const f32x4*)&lnb[cb+4];
    f32x4 za = da*inv*ga + ba, zb = db*inv*gb + bb;
    half8 hz = { (f16)za[0],(f16)za[1],(f16)za[2],(f16)za[3],
                 (f16)zb[0],(f16)zb[1],(f16)zb[2],(f16)zb[3] };
    *(half8*)&zl[row][cb] = hz;
  }
  __syncthreads();   // zl ready for all waves; also separates Wkts reads from y1 writes
  // ---- W1: 32 nt over 8 waves = 4 nt/wave; 2 M-tiles share each B-frag (1:2)
  half8 aza[4], azb[4];
  #pragma unroll
  for (int kc = 0; kc < 4; ++kc) {
    aza[kc] = *(const half8*)&zl[rlo][kc*32 + row4*8];
    azb[kc] = *(const half8*)&zl[16 + rlo][kc*32 + row4*8];
  }
  #pragma unroll
  for (int ntl = 0; ntl < 4; ++ntl) {
    int col = (w*4 + ntl)*16 + rlo;
    f32x4 accA = {0.f,0.f,0.f,0.f}, accB = {0.f,0.f,0.f,0.f};
    #pragma unroll
    for (int kc = 0; kc < 4; ++kc) {
      half8 b = *(const half8*)&W1t_l[(size_t)col*128 + kc*32 + row4*8];
      accA = __builtin_amdgcn_mfma_f32_16x16x32_f16(aza[kc], b, accA, 0, 0, 0);
      accB = __builtin_amdgcn_mfma_f32_16x16x32_f16(azb[kc], b, accB, 0, 0, 0);
    }
    float bias = b1_l[col];
    #pragma unroll
    for (int j = 0; j < 4; ++j) {
      y1[row4*4 + j][col]      = (f16)gelu_tanh(accA[j] + bias);
      y1[16 + row4*4 + j][col] = (f16)gelu_tanh(accB[j] + bias);
    }
  }
  __syncthreads();
  // ---- W2: 1 col-tile/wave; K-loop: 1 B-load + 2 ds_read + 2 MFMA
  {
    int col = w*16 + rlo;
    f32x4 accA = {0.f,0.f,0.f,0.f}, accB = {0.f,0.f,0.f,0.f};
    #pragma unroll
    for (int kc2 = 0; kc2 < 16; ++kc2) {
      half8 b   = *(const half8*)&W2t_l[(size_t)col*512 + kc2*32 + row4*8];
      half8 a2a = *(const half8*)&y1[rlo][kc2*32 + row4*8];
      half8 a2b = *(const half8*)&y1[16 + rlo][kc2*32 + row4*8];
      accA = __builtin_amdgcn_mfma_f32_16x16x32_f16(a2a, b, accA, 0, 0, 0);
      accB = __builtin_amdgcn_mfma_f32_16x16x32_f16(a2b, b, accB, 0, 0, 0);
    }
    float bias = b2_l[col];
    #pragma unroll
    for (int j = 0; j < 4; ++j) {
      size_t na = (size_t)(n0 + row4*4 + j);
      size_t nb = (size_t)(n0 + 16 + row4*4 + j);
      hout[na*128 + col] = accA[j] + bias + hin[na*128 + col];
      hout[nb*128 + col] = accB[j] + bias + hin[nb*128 + col];
    }
  }
}

// ---------------- readout ------------------------------------------------------------
__global__ __launch_bounds__(256) void readout_kernel(const float* __restrict__ h,
    const float* __restrict__ Wr, const float* __restrict__ br, float* __restrict__ out) {
  int n = blockIdx.x*256 + threadIdx.x;
  f32x4 acc = {0.f,0.f,0.f,0.f};
  #pragma unroll
  for (int cb = 0; cb < 32; ++cb) {
    f32x4 hv = *(const f32x4*)(h + (size_t)n*128 + cb*4);
    f32x4 wv = *(const f32x4*)(Wr + cb*4);
    acc += hv*wv;
  }
  out[n] = acc[0]+acc[1]+acc[2]+acc[3] + br[0];
}

extern "C" void kernel_launch(void* const* d_in, const int* in_sizes, int n_in,
                              void* d_out, int out_size, void* d_ws, size_t ws_size,
                              hipStream_t stream) {
  const float* x   = (const float*)d_in[0];
  const float* pos = (const float*)d_in[1];
  const float* We  = (const float*)d_in[3];
  const float* Wb1 = (const float*)d_in[4];
  const float* bb1 = (const float*)d_in[5];
  const float* Wb2 = (const float*)d_in[6];
  const float* bb2 = (const float*)d_in[7];
  const float* Wk  = (const float*)d_in[8];
  const float* lng = (const float*)d_in[9];
  const float* lnb = (const float*)d_in[10];
  const float* W1  = (const float*)d_in[11];
  const float* b1  = (const float*)d_in[12];
  const float* W2  = (const float*)d_in[13];
  const float* b2  = (const float*)d_in[14];
  const float* Wr  = (const float*)d_in[15];
  const float* br  = (const float*)d_in[16];
  float* out = (float*)d_out;

  char* p = (char*)d_ws;
  int*   srci  = (int*)p;     p += (size_t)EE*4;
  float* dedge = (float*)p;   p += (size_t)EE*4;
  f16*   kernA = (f16*)p;     p += (size_t)EE*128*2;
  float* hA    = (float*)p;   p += (size_t)NN*128*4;
  float* hB    = (float*)p;   p += (size_t)NN*128*4;
  f16* Wb2t    = (f16*)p;     p += (size_t)16384*2;
  f16* Wkt     = (f16*)p;     p += (size_t)65536*2;
  f16* W1t     = (f16*)p;     p += (size_t)262144*2;
  f16* W2t     = (f16*)p;     p += (size_t)262144*2;
  float* posx  = (float*)p;   p += (size_t)NN*4;
  float* posy  = (float*)p;   p += (size_t)NN*4;
  float* posz  = (float*)p;   p += (size_t)NN*4;

  possoa_kernel<<<NN/256, 256, 0, stream>>>(pos, posx, posy, posz);
  prep_kernel<<<2368, 256, 0, stream>>>(Wb2, Wk, W1, W2, Wb2t, Wkt, W1t, W2t);
  knn_kernel<<<NN/4, 256, 0, stream>>>(posx, posy, posz, srci, dedge);
  basis_kernel<<<2048, 256, 0, stream>>>(dedge, Wb1, bb1, Wb2t, bb2, kernA);
  embed_kernel<<<NN/8, 256, 0, stream>>>(x, We, hA);
  float* hin = hA;
  for (int lyr = 0; lyr < NL; ++lyr) {
    float* hout = (hin == hA) ? hB : hA;
    layer_kernel<<<NN/32, 512, 0, stream>>>(kernA, Wkt + lyr*16384, srci, hin,
        lng + lyr*128, lnb + lyr*128,
        W1t + (size_t)lyr*65536, b1 + lyr*512, W2t + (size_t)lyr*65536, b2 + lyr*128, hout);
    hin = hout;
  }
  readout_kernel<<<NN/256, 256, 0, stream>>>(hin, Wr, br, out);
}